// Round 1
// baseline (304.971 us; speedup 1.0000x reference)
//
#include <hip/hip_runtime.h>
#include <stdint.h>

#define N_VOX 262144
#define CCH 64
#define KOFF 27

typedef short v8s __attribute__((ext_vector_type(8)));
typedef float v4f __attribute__((ext_vector_type(4)));
typedef int   v4i __attribute__((ext_vector_type(4)));

__device__ __forceinline__ unsigned short f2bf(float f) {
  unsigned u = __float_as_uint(f);
  u += 0x7fff + ((u >> 16) & 1);   // RNE
  return (unsigned short)(u >> 16);
}

// --- deterministic sniff of the mask buffer's dtype (byte-bool vs 32-bit) ---
__global__ void prep_flag_k(const unsigned* __restrict__ m, int* __restrict__ flag) {
  if (threadIdx.x == 0) {
    int wordlike = 1;  // int32 0/1 or float32 0.0/1.0
    for (int i = 0; i < 256; ++i) {
      unsigned v = m[i];
      if (v > 1u && v != 0x3f800000u) { wordlike = 0; break; }
    }
    *flag = wordlike ? 0 : 2;   // 0: read as u32 words, 2: read as bytes
  }
}

__global__ void prep_mask_k(const void* __restrict__ m, const int* __restrict__ flag,
                            unsigned char* __restrict__ mb, int n) {
  int f = *flag;
  for (int i = blockIdx.x * blockDim.x + threadIdx.x; i < n; i += gridDim.x * blockDim.x) {
    unsigned char v;
    if (f == 2) v = (((const unsigned char*)m)[i] != 0);
    else        v = (((const unsigned*)m)[i] != 0u);
    mb[i] = v;
  }
}

// --- features fp32 -> bf16 table (halves gather traffic, frags load direct) ---
__global__ void prep_feat_k(const float* __restrict__ src, unsigned short* __restrict__ dst, int n8) {
  int i = blockIdx.x * blockDim.x + threadIdx.x;
  if (i >= n8) return;
  const float4* s4 = (const float4*)src;
  float4 a = s4[i * 2], b = s4[i * 2 + 1];
  v8s v;
  v[0] = (short)f2bf(a.x); v[1] = (short)f2bf(a.y);
  v[2] = (short)f2bf(a.z); v[3] = (short)f2bf(a.w);
  v[4] = (short)f2bf(b.x); v[5] = (short)f2bf(b.y);
  v[6] = (short)f2bf(b.z); v[7] = (short)f2bf(b.w);
  ((v8s*)dst)[i] = v;
}

// --- W [27][cin][cout] fp32 -> Wt bf16 [27][cout][cin], XOR-swizzled for LDS ---
__global__ void prep_w_k(const float* __restrict__ w, unsigned short* __restrict__ wt) {
  int i = blockIdx.x * blockDim.x + threadIdx.x;
  if (i >= KOFF * CCH * CCH) return;
  int k = i >> 12, rem = i & 4095, kk = rem >> 6, col = rem & 63;
  wt[(k << 12) + (col << 6) + (kk ^ ((col & 7) << 3))] = f2bf(w[i]);
}

// --- one sparse-conv layer: out[n] = sum_k mask[k][n] * src[nbr[k][n]] @ W[k] + b ---
// LAYER==1: out = bf16 h (ws). LAYER==2: out = f32 + residual(features).
template <int LAYER>
__global__ void conv_layer_k(const v8s* __restrict__ src, const int* __restrict__ nbr,
                             const unsigned char* __restrict__ mb,
                             const v4i* __restrict__ wt, const float* __restrict__ bias,
                             const float* __restrict__ resid, void* __restrict__ outp) {
  __shared__ v4i ldsB[2][512];   // double-buffered Wt_k: 2 x 8 KiB
  const int tid = threadIdx.x;
  const int lane = tid & 63;
  const int wv = tid >> 6;
  const int l15 = lane & 15;
  const int g = lane >> 4;
  const int rowbase = blockIdx.x * 256 + wv * 64;

  // prologue: stage k=0
  {
    v4i w0 = wt[tid], w1 = wt[256 + tid];
    ldsB[0][tid] = w0;
    ldsB[0][256 + tid] = w1;
  }
  __syncthreads();

  v4f acc[4][4] = {};   // [rowtile][coltile], fp32 MFMA accumulators

  int cur = 0;
  for (int k = 0; k < KOFF; ++k) {
    const bool more = (k + 1 < KOFF);
    v4i nw0, nw1;
    if (more) { nw0 = wt[(k + 1) * 512 + tid]; nw1 = wt[(k + 1) * 512 + 256 + tid]; }

    // B fragments from LDS (swizzled -> conflict-free b128 reads), held in regs
    const short* Bs = (const short*)ldsB[cur];
    v8s bf[4][2];
#pragma unroll
    for (int ct = 0; ct < 4; ++ct) {
      int col = ct * 16 + l15;
      int sw = (col & 7) << 3;
      int base = col << 6;
      bf[ct][0] = *(const v8s*)(Bs + base + ((g * 8) ^ sw));
      bf[ct][1] = *(const v8s*)(Bs + base + ((32 + g * 8) ^ sw));
    }

    const int kN = k * N_VOX;
#pragma unroll
    for (int rt = 0; rt < 4; ++rt) {
      int grow = rowbase + rt * 16 + l15;
      int idx = nbr[kN + grow];
      v8s a0 = {}, a1 = {};
      if (mb[kN + grow]) {          // masked rows: skip the gather entirely
        a0 = src[idx * 8 + g];      // k = g*8 .. g*8+7      (A-frag layout direct)
        a1 = src[idx * 8 + 4 + g];  // k = 32+g*8 ..
      }
#pragma unroll
      for (int ct = 0; ct < 4; ++ct) {
        acc[rt][ct] = __builtin_amdgcn_mfma_f32_16x16x32_bf16(a0, bf[ct][0], acc[rt][ct], 0, 0, 0);
        acc[rt][ct] = __builtin_amdgcn_mfma_f32_16x16x32_bf16(a1, bf[ct][1], acc[rt][ct], 0, 0, 0);
      }
    }

    // stage k+1 into the other buffer; one barrier per offset
    if (more) {
      ldsB[cur ^ 1][tid] = nw0;
      ldsB[cur ^ 1][256 + tid] = nw1;
    }
    __syncthreads();
    if (more) cur ^= 1;
  }

  float bv[4];
#pragma unroll
  for (int ct = 0; ct < 4; ++ct) bv[ct] = bias[ct * 16 + l15];

#pragma unroll
  for (int rt = 0; rt < 4; ++rt) {
    int row0 = rowbase + rt * 16 + g * 4;   // D row = (lane>>4)*4 + i
#pragma unroll
    for (int ct = 0; ct < 4; ++ct) {
      int col = ct * 16 + l15;              // D col = lane & 15
#pragma unroll
      for (int i = 0; i < 4; ++i) {
        float v = acc[rt][ct][i] + bv[ct];
        int o = (row0 + i) * CCH + col;
        if (LAYER == 1) ((unsigned short*)outp)[o] = f2bf(v);
        else            ((float*)outp)[o] = v + resid[o];
      }
    }
  }
}

extern "C" void kernel_launch(void* const* d_in, const int* in_sizes, int n_in,
                              void* d_out, int out_size, void* d_ws, size_t ws_size,
                              hipStream_t stream) {
  const float* feat = (const float*)d_in[0];
  const int* nbr    = (const int*)d_in[1];
  const void* mask  = d_in[2];
  const float* w1   = (const float*)d_in[3];
  const float* b1   = (const float*)d_in[4];
  const float* w2   = (const float*)d_in[5];
  const float* b2   = (const float*)d_in[6];

  char* ws = (char*)d_ws;
  unsigned short* featb = (unsigned short*)ws;                    // 33,554,432 B
  unsigned short* hb    = (unsigned short*)(ws + 33554432);       // 33,554,432 B
  unsigned char*  maskb = (unsigned char*)(ws + 67108864);        //  7,077,888 B
  unsigned short* wt1   = (unsigned short*)(ws + 74186752);       //    221,184 B
  unsigned short* wt2   = (unsigned short*)(ws + 74407936);       //    221,184 B
  int*            flag  = (int*)(ws + 74629120);

  prep_flag_k<<<1, 64, 0, stream>>>((const unsigned*)mask, flag);
  prep_mask_k<<<4096, 256, 0, stream>>>(mask, flag, maskb, KOFF * N_VOX);
  prep_feat_k<<<8192, 256, 0, stream>>>(feat, featb, N_VOX * CCH / 8);
  prep_w_k<<<432, 256, 0, stream>>>(w1, wt1);
  prep_w_k<<<432, 256, 0, stream>>>(w2, wt2);

  conv_layer_k<1><<<1024, 256, 0, stream>>>((const v8s*)featb, nbr, maskb,
                                            (const v4i*)wt1, b1, nullptr, (void*)hb);
  conv_layer_k<2><<<1024, 256, 0, stream>>>((const v8s*)hb, nbr, maskb,
                                            (const v4i*)wt2, b2, feat, (void*)d_out);
}

// Round 2
// 216.457 us; speedup vs baseline: 1.4089x; 1.4089x over previous
//
#include <hip/hip_runtime.h>
#include <stdint.h>

#define N_VOX 262144
#define CCH 64
#define KOFF 27

typedef short v8s __attribute__((ext_vector_type(8)));
typedef float v4f __attribute__((ext_vector_type(4)));
typedef int   v4i __attribute__((ext_vector_type(4)));

__device__ __forceinline__ unsigned short f2bf(float f) {
  unsigned u = __float_as_uint(f);
  u += 0x7fff + ((u >> 16) & 1);   // RNE
  return (unsigned short)(u >> 16);
}

// --- deterministic sniff of the mask buffer's dtype (byte-bool vs 32-bit) ---
__global__ void prep_flag_k(const unsigned* __restrict__ m, int* __restrict__ flag) {
  if (threadIdx.x == 0) {
    int wordlike = 1;  // int32 0/1 or float32 0.0/1.0
    for (int i = 0; i < 256; ++i) {
      unsigned v = m[i];
      if (v > 1u && v != 0x3f800000u) { wordlike = 0; break; }
    }
    *flag = wordlike ? 0 : 2;   // 0: read as u32 words, 2: read as bytes
  }
}

__global__ void prep_mask_k(const void* __restrict__ m, const int* __restrict__ flag,
                            unsigned char* __restrict__ mb, int n) {
  int f = *flag;
  for (int i = blockIdx.x * blockDim.x + threadIdx.x; i < n; i += gridDim.x * blockDim.x) {
    unsigned char v;
    if (f == 2) v = (((const unsigned char*)m)[i] != 0);
    else        v = (((const unsigned*)m)[i] != 0u);
    mb[i] = v;
  }
}

// --- features fp32 -> bf16 table (halves gather traffic, frags load direct) ---
__global__ void prep_feat_k(const float* __restrict__ src, unsigned short* __restrict__ dst, int n8) {
  int i = blockIdx.x * blockDim.x + threadIdx.x;
  if (i >= n8) return;
  const float4* s4 = (const float4*)src;
  float4 a = s4[i * 2], b = s4[i * 2 + 1];
  v8s v;
  v[0] = (short)f2bf(a.x); v[1] = (short)f2bf(a.y);
  v[2] = (short)f2bf(a.z); v[3] = (short)f2bf(a.w);
  v[4] = (short)f2bf(b.x); v[5] = (short)f2bf(b.y);
  v[6] = (short)f2bf(b.z); v[7] = (short)f2bf(b.w);
  ((v8s*)dst)[i] = v;
}

// --- W [27][cin][cout] fp32 -> Wt bf16 [27][cout][cin], XOR-swizzled for LDS ---
__global__ void prep_w_k(const float* __restrict__ w, unsigned short* __restrict__ wt) {
  int i = blockIdx.x * blockDim.x + threadIdx.x;
  if (i >= KOFF * CCH * CCH) return;
  int k = i >> 12, rem = i & 4095, kk = rem >> 6, col = rem & 63;
  wt[(k << 12) + (col << 6) + (kk ^ ((col & 7) << 3))] = f2bf(w[i]);
}

// --- one sparse-conv layer, software-pipelined ---
// Per block: 128 rows (4 waves x 32). Pipeline: idx/mask 2 ahead, A-gathers 1
// ahead (second register set), W 1 ahead. One barrier per offset.
// LAYER==1: out = bf16 h (ws). LAYER==2: out = f32 + bias + residual.
template <int LAYER>
__global__ __launch_bounds__(256, 4)
void conv_layer_k(const v8s* __restrict__ src, const int* __restrict__ nbr,
                  const unsigned char* __restrict__ mb,
                  const v4i* __restrict__ wt, const float* __restrict__ bias,
                  const float* __restrict__ resid, void* __restrict__ outp) {
  __shared__ v4i ldsB[2][512];   // double-buffered Wt_k: 2 x 8 KiB
  const int tid = threadIdx.x;
  const int lane = tid & 63;
  const int wv = tid >> 6;
  const int l15 = lane & 15;
  const int g = lane >> 4;
  const int rowbase = blockIdx.x * 128 + wv * 32;
  const int r0 = rowbase + l15;
  const int r1 = rowbase + 16 + l15;

  // stage B(k=0)
  ldsB[0][tid] = wt[tid];
  ldsB[0][256 + tid] = wt[256 + tid];

  // k=0 gathers (current set)
  v8s a0c = {}, a1c = {}, a2c = {}, a3c = {};
  {
    int i0 = nbr[r0], i1 = nbr[r1];
    if (mb[r0]) { a0c = src[i0 * 8 + g]; a1c = src[i0 * 8 + 4 + g]; }
    if (mb[r1]) { a2c = src[i1 * 8 + g]; a3c = src[i1 * 8 + 4 + g]; }
  }
  // k=1 idx/mask (pending)
  int j0 = nbr[N_VOX + r0], j1 = nbr[N_VOX + r1];
  bool n0 = mb[N_VOX + r0], n1 = mb[N_VOX + r1];

  v4f acc0[4] = {}, acc1[4] = {};
  __syncthreads();

  int cur = 0;
  for (int k = 0; k < KOFF; ++k) {
    const int kc1 = (k + 1 < KOFF) ? k + 1 : KOFF - 1;
    const int kc2 = (k + 2 < KOFF) ? k + 2 : KOFF - 1;

    // W prefetch for k+1
    v4i nw0 = wt[kc1 * 512 + tid];
    v4i nw1 = wt[kc1 * 512 + 256 + tid];

    // idx/mask prefetch for k+2
    int t0 = nbr[kc2 * N_VOX + r0], t1 = nbr[kc2 * N_VOX + r1];
    bool u0 = mb[kc2 * N_VOX + r0], u1 = mb[kc2 * N_VOX + r1];

    // A-gathers for k+1 (idx/mask loaded one iteration ago)
    v8s a0n = {}, a1n = {}, a2n = {}, a3n = {};
    if (k + 1 < KOFF) {
      if (n0) { a0n = src[j0 * 8 + g]; a1n = src[j0 * 8 + 4 + g]; }
      if (n1) { a2n = src[j1 * 8 + g]; a3n = src[j1 * 8 + 4 + g]; }
    }

    // B fragments for k from LDS (swizzled -> conflict-free b128 reads)
    const short* Bs = (const short*)ldsB[cur];
    v8s bf0[4], bf1[4];
#pragma unroll
    for (int ct = 0; ct < 4; ++ct) {
      int col = ct * 16 + l15;
      int sw = (col & 7) << 3;
      int base = col << 6;
      bf0[ct] = *(const v8s*)(Bs + base + ((g * 8) ^ sw));
      bf1[ct] = *(const v8s*)(Bs + base + ((32 + g * 8) ^ sw));
    }

#pragma unroll
    for (int ct = 0; ct < 4; ++ct) {
      acc0[ct] = __builtin_amdgcn_mfma_f32_16x16x32_bf16(a0c, bf0[ct], acc0[ct], 0, 0, 0);
      acc0[ct] = __builtin_amdgcn_mfma_f32_16x16x32_bf16(a1c, bf1[ct], acc0[ct], 0, 0, 0);
      acc1[ct] = __builtin_amdgcn_mfma_f32_16x16x32_bf16(a2c, bf0[ct], acc1[ct], 0, 0, 0);
      acc1[ct] = __builtin_amdgcn_mfma_f32_16x16x32_bf16(a3c, bf1[ct], acc1[ct], 0, 0, 0);
    }

    // stage B(k+1); one barrier per offset
    ldsB[cur ^ 1][tid] = nw0;
    ldsB[cur ^ 1][256 + tid] = nw1;
    __syncthreads();
    cur ^= 1;

    // rotate pipeline registers
    a0c = a0n; a1c = a1n; a2c = a2n; a3c = a3n;
    j0 = t0; j1 = t1; n0 = u0; n1 = u1;
  }

  float bv[4];
#pragma unroll
  for (int ct = 0; ct < 4; ++ct) bv[ct] = bias[ct * 16 + l15];

#pragma unroll
  for (int rt = 0; rt < 2; ++rt) {
    int row0 = rowbase + rt * 16 + g * 4;   // D row = (lane>>4)*4 + i
#pragma unroll
    for (int ct = 0; ct < 4; ++ct) {
      int col = ct * 16 + l15;              // D col = lane & 15
      const v4f& a = rt ? acc1[ct] : acc0[ct];
#pragma unroll
      for (int i = 0; i < 4; ++i) {
        float v = a[i] + bv[ct];
        int o = (row0 + i) * CCH + col;
        if (LAYER == 1) ((unsigned short*)outp)[o] = f2bf(v);
        else            ((float*)outp)[o] = v + resid[o];
      }
    }
  }
}

extern "C" void kernel_launch(void* const* d_in, const int* in_sizes, int n_in,
                              void* d_out, int out_size, void* d_ws, size_t ws_size,
                              hipStream_t stream) {
  const float* feat = (const float*)d_in[0];
  const int* nbr    = (const int*)d_in[1];
  const void* mask  = d_in[2];
  const float* w1   = (const float*)d_in[3];
  const float* b1   = (const float*)d_in[4];
  const float* w2   = (const float*)d_in[5];
  const float* b2   = (const float*)d_in[6];

  char* ws = (char*)d_ws;
  unsigned short* featb = (unsigned short*)ws;                    // 33,554,432 B
  unsigned short* hb    = (unsigned short*)(ws + 33554432);       // 33,554,432 B
  unsigned char*  maskb = (unsigned char*)(ws + 67108864);        //  7,077,888 B
  unsigned short* wt1   = (unsigned short*)(ws + 74186752);       //    221,184 B
  unsigned short* wt2   = (unsigned short*)(ws + 74407936);       //    221,184 B
  int*            flag  = (int*)(ws + 74629120);

  prep_flag_k<<<1, 64, 0, stream>>>((const unsigned*)mask, flag);
  prep_mask_k<<<4096, 256, 0, stream>>>(mask, flag, maskb, KOFF * N_VOX);
  prep_feat_k<<<8192, 256, 0, stream>>>(feat, featb, N_VOX * CCH / 8);
  prep_w_k<<<432, 256, 0, stream>>>(w1, wt1);
  prep_w_k<<<432, 256, 0, stream>>>(w2, wt2);

  conv_layer_k<1><<<2048, 256, 0, stream>>>((const v8s*)featb, nbr, maskb,
                                            (const v4i*)wt1, b1, nullptr, (void*)hb);
  conv_layer_k<2><<<2048, 256, 0, stream>>>((const v8s*)hb, nbr, maskb,
                                            (const v4i*)wt2, b2, feat, (void*)d_out);
}